// Round 10
// baseline (140.351 us; speedup 1.0000x reference)
//
#include <hip/hip_runtime.h>

#define BATCH 4
#define NPTS 16384
#define MPTS 16384
#define NH 32
#define NK 15
#define NF 64
#define NC 64

typedef short short8 __attribute__((ext_vector_type(8)));
typedef float floatx4 __attribute__((ext_vector_type(4)));

__device__ __forceinline__ unsigned short f2bf(float x) {
    unsigned int u = __builtin_bit_cast(unsigned int, x);
    u = u + 0x7FFFu + ((u >> 16) & 1u);   // RNE
    return (unsigned short)(u >> 16);
}

// pack two floats -> bf16x2 dword by truncation (1 v_perm)
__device__ __forceinline__ unsigned pack_trunc(float lo, float hi) {
    return __builtin_amdgcn_perm(__builtin_bit_cast(unsigned, hi),
                                 __builtin_bit_cast(unsigned, lo), 0x07060302u);
}

// ---------- fused prep: blocks [0,32) = V re-layout; [32, 2080) = feat fp32->bf16 ----------
__global__ void prep_kernel(const float* __restrict__ kv, const float* __restrict__ feat,
                            unsigned short* __restrict__ vp, unsigned short* __restrict__ featbf) {
    if (blockIdx.x < 32) {
        // kappa = f*16 + k (k padded to 16, zero for k==15). KF = 1024 -> 32 mfma steps.
        const int gid = blockIdx.x * 256 + threadIdx.x;        // 8192 threads
        const int lane = gid & 63;
        const int ct   = (gid >> 6) & 3;
        const int kk   = gid >> 8;                             // 0..31
        const int c    = ct * 16 + (lane & 15);
        const int kap0 = kk * 32 + (lane >> 4) * 8;
        unsigned int o[4];
        #pragma unroll
        for (int jj = 0; jj < 4; jj++) {
            unsigned short lo, hi;
            {
                const int kap = kap0 + jj * 2;
                const int f = kap >> 4, k = kap & 15;
                lo = (k < NK) ? f2bf(kv[((size_t)(k * NF + f)) * NC + c]) : (unsigned short)0;
            }
            {
                const int kap = kap0 + jj * 2 + 1;
                const int f = kap >> 4, k = kap & 15;
                hi = (k < NK) ? f2bf(kv[((size_t)(k * NF + f)) * NC + c]) : (unsigned short)0;
            }
            o[jj] = (unsigned)lo | ((unsigned)hi << 16);
        }
        *(uint4*)(vp + (size_t)gid * 8) = make_uint4(o[0], o[1], o[2], o[3]);
    } else {
        const int gid = (blockIdx.x - 32) * 256 + threadIdx.x; // 524288 threads x 8 elems
        const size_t base = (size_t)gid * 8;
        float4 a = *(const float4*)(feat + base);
        float4 b = *(const float4*)(feat + base + 4);
        uint4 o;
        o.x = (unsigned)f2bf(a.x) | ((unsigned)f2bf(a.y) << 16);
        o.y = (unsigned)f2bf(a.z) | ((unsigned)f2bf(a.w) << 16);
        o.z = (unsigned)f2bf(b.x) | ((unsigned)f2bf(b.y) << 16);
        o.w = (unsigned)f2bf(b.z) | ((unsigned)f2bf(b.w) << 16);
        *(uint4*)(featbf + base) = o;
    }
}

// ---------- main kernel ----------
__global__ __launch_bounds__(256, 5) void kpconv_kernel(
    const float* __restrict__ points,          // [B,N,3]
    const unsigned short* __restrict__ featbf, // [B,N,F] bf16 (ws)
    const float* __restrict__ outpts,          // [B,M,3]
    const float* __restrict__ kpts,            // [K,3]
    const unsigned short* __restrict__ vp,     // einsum2 B-frag-ordered V bf16 (ws)
    const int*   __restrict__ nbr,             // [B,M,H]
    float* __restrict__ out)                   // [B,M,C]
{
    // awf: wf in einsum2 A-frag order for ONE kappa-half: [kk 0..15][chunk(swizzled)][8]
    // Prologue aliases it as rel4[512] float4; epilogue aliases it as ob[16*68] float.
    __shared__ __align__(16) unsigned short awf[16 * 512];    // 16384 B
    // feat_s per wave: 4 f-chunks (stride 336 shorts = 672 B, 16B-aligned, bank skew
    // 168 dwords ≡ 8 mod 32) x (8 rows x 40 shorts). Stores 2-way (free); b128 reads
    // single-instruction, bank-balanced.
    __shared__ __align__(16) unsigned short feat_s[4 * 1344]; // 10752 B
    __shared__ int   idx_s[512];                              //  2048 B
    __shared__ float opt_s[48];
    __shared__ float kp_s[48];

    const int tid   = threadIdx.x;
    // XCD-aware partition: round-robin dispatch sends blockIdx ≡ x (mod 8) to XCD x,
    // so batch = blockIdx & 3 pins each XCD's L2 to a single batch's 2 MB feature slice.
    const int batch = blockIdx.x & 3;
    const int m0    = (blockIdx.x >> 2) << 4;

    if (tid < 48) kp_s[tid] = (tid < 45) ? kpts[tid] : 1e9f;   // sentinel -> w=0 for k=15
    if (tid >= 64 && tid < 112)
        opt_s[tid - 64] = outpts[(size_t)(batch * MPTS + m0) * 3 + (tid - 64)];
    {
        const size_t nb = (size_t)(batch * MPTS + m0) * NH;
        idx_s[tid]       = nbr[nb + tid];
        idx_s[256 + tid] = nbr[nb + 256 + tid];
    }
    __syncthreads();   // B1: idx/opt/kp ready

    const int g    = tid >> 6;    // wave id; feat_s partition g is wave-private
    const int lane = tid & 63;
    const int cl   = lane & 15;
    const int q    = lane >> 4;
    const int sa   = cl;          // h-pair handled by this lane in staging
    const int sfc  = q;           // f-chunk of 8 shorts in staging

    const unsigned short* fbase = featbf + (size_t)(batch * NPTS) * NF;

    // ---- issue iter-0 gather immediately (consumed after 2 barriers of latency) ----
    uint4 pra, prb;
    {
        const int srow = g * 32 + sa * 2;                      // r=0, fh=0
        const int id0 = idx_s[srow], id1 = idx_s[srow + 1];
        pra = *(const uint4*)(fbase + (size_t)id0 * NF + sfc * 8);
        prb = *(const uint4*)(fbase + (size_t)id1 * NF + sfc * 8);
    }

    // ---- stage rel coords into awf alias ----
    float4* rel4 = (float4*)awf;
    #pragma unroll
    for (int rr = 0; rr < 2; rr++) {
        const int row = tid * 2 + rr;            // 0..511 = p*32 + h
        const int id  = idx_s[row];
        const int pm  = row >> 5;
        const float* pp = points + ((size_t)(batch * NPTS) + id) * 3;
        rel4[row] = make_float4(pp[0] - opt_s[pm * 3 + 0],
                                pp[1] - opt_s[pm * 3 + 1],
                                pp[2] - opt_s[pm * 3 + 2], 0.f);
    }
    __syncthreads();   // B2: rel ready

    // ---- compute all w A-frags for this wave's 4 points (held in registers) ----
    short8 af[4];
    {
        const float kx = kp_s[cl * 3 + 0];
        const float ky = kp_s[cl * 3 + 1];
        const float kz = kp_s[cl * 3 + 2];
        #pragma unroll
        for (int rp = 0; rp < 4; rp++) {
            const int p = rp * 4 + g;
            float wv[8];
            #pragma unroll
            for (int j = 0; j < 8; j++) {
                const float4 rr = rel4[p * 32 + q * 8 + j];    // broadcast across cl
                const float dx = rr.x - kx, dy = rr.y - ky, dz = rr.z - kz;
                const float d2 = dx * dx + dy * dy + dz * dz;
                wv[j] = fmaxf(1.f - __builtin_amdgcn_sqrtf(d2), 0.f);  // EXTENT=1
            }
            uint4 ua;
            ua.x = pack_trunc(wv[0], wv[1]);
            ua.y = pack_trunc(wv[2], wv[3]);
            ua.z = pack_trunc(wv[4], wv[5]);
            ua.w = pack_trunc(wv[6], wv[7]);
            af[rp] = __builtin_bit_cast(short8, ua);
        }
    }
    __syncthreads();   // B3: rel4 dead -> awf free for einsum1 output

    floatx4 acc0 = {0.f, 0.f, 0.f, 0.f};
    floatx4 acc1 = {0.f, 0.f, 0.f, 0.f};
    const unsigned short* vpg = vp + g * 512 + lane * 8;
    unsigned short* dp = &feat_s[g * 1344 + sfc * 336 + sa * 2];   // chunk sfc, h-pair sa

    #pragma unroll
    for (int fh = 0; fh < 2; fh++) {
        #pragma unroll
        for (int r = 0; r < 4; r++) {
            const int p = r * 4 + g;

            // (a) stage this iter's f-half from prefetched regs (wave-private LDS, no barrier)
            *(unsigned*)(dp + 0 * 40) = __builtin_amdgcn_perm(prb.x, pra.x, 0x05040100u);
            *(unsigned*)(dp + 1 * 40) = __builtin_amdgcn_perm(prb.x, pra.x, 0x07060302u);
            *(unsigned*)(dp + 2 * 40) = __builtin_amdgcn_perm(prb.y, pra.y, 0x05040100u);
            *(unsigned*)(dp + 3 * 40) = __builtin_amdgcn_perm(prb.y, pra.y, 0x07060302u);
            *(unsigned*)(dp + 4 * 40) = __builtin_amdgcn_perm(prb.z, pra.z, 0x05040100u);
            *(unsigned*)(dp + 5 * 40) = __builtin_amdgcn_perm(prb.z, pra.z, 0x07060302u);
            *(unsigned*)(dp + 6 * 40) = __builtin_amdgcn_perm(prb.w, pra.w, 0x05040100u);
            *(unsigned*)(dp + 7 * 40) = __builtin_amdgcn_perm(prb.w, pra.w, 0x07060302u);

            // (b) prefetch next iter's gathers
            if (!(fh == 1 && r == 3)) {
                const int nit = fh * 4 + r + 1;
                const int nfh = nit >> 2, nr = nit & 3;
                const int srow = (nr * 4 + g) * 32 + sa * 2;
                const int id0 = idx_s[srow], id1 = idx_s[srow + 1];
                pra = *(const uint4*)(fbase + (size_t)id0 * NF + nfh * 32 + sfc * 8);
                prb = *(const uint4*)(fbase + (size_t)id1 * NF + nfh * 32 + sfc * 8);
            }

            // (c) einsum1: 2 f-tiles of 16 for point p
            #pragma unroll
            for (int t = 0; t < 2; t++) {
                const unsigned short* brd =
                    &feat_s[g * 1344 + (2 * t + (cl >> 3)) * 336 + (cl & 7) * 40 + q * 8];
                const uint4 ub = *(const uint4*)brd;
                floatx4 dd = {0.f, 0.f, 0.f, 0.f};
                dd = __builtin_amdgcn_mfma_f32_16x16x32_bf16(af[r], __builtin_bit_cast(short8, ub), dd, 0, 0, 0);
                const int kk    = 8 * t + (cl >> 1);               // local kappa-chunk 0..15
                const int q2    = (2 * cl + (q >> 1)) & 3;
                const int chunk = (p ^ kk) | (q2 << 4);
                unsigned* wp = (unsigned*)awf + kk * 256 + chunk * 4 + (q & 1) * 2;
                wp[0] = pack_trunc(dd[0], dd[1]);
                wp[1] = pack_trunc(dd[2], dd[3]);
            }
        }

        // ---- einsum2 over this kappa-half; vp double-buffered in regs across the barrier ----
        uint4 v0 = *(const uint4*)(vpg + (size_t)(fh * 16 + 0) * 2048);
        uint4 v1 = *(const uint4*)(vpg + (size_t)(fh * 16 + 1) * 2048);
        __syncthreads();   // B4/B6: awf half complete
        #pragma unroll
        for (int kk = 0; kk < 16; kk++) {
            const int chunk = (cl ^ kk) | (lane & 48);
            const uint4 uA = *(const uint4*)&awf[kk * 512 + chunk * 8];
            const uint4 uB = v0;
            v0 = v1;
            if (kk < 14) v1 = *(const uint4*)(vpg + (size_t)(fh * 16 + kk + 2) * 2048);
            if (kk & 1)
                acc1 = __builtin_amdgcn_mfma_f32_16x16x32_bf16(
                    __builtin_bit_cast(short8, uA), __builtin_bit_cast(short8, uB), acc1, 0, 0, 0);
            else
                acc0 = __builtin_amdgcn_mfma_f32_16x16x32_bf16(
                    __builtin_bit_cast(short8, uA), __builtin_bit_cast(short8, uB), acc0, 0, 0, 0);
        }
        __syncthreads();   // B5/B7: einsum2 reads done -> awf reusable (fh=1 / epilogue)
    }

    // ---- coalesced epilogue: stage via awf (stride-68 skew), store full 256B rows ----
    float* ob = (float*)awf;                    // need 16*68 = 1088 floats (4352 B)
    #pragma unroll
    for (int ri = 0; ri < 4; ri++)
        ob[(q * 4 + ri) * 68 + g * 16 + cl] = acc0[ri] + acc1[ri];
    __syncthreads();   // B8: staged
    {
        const int row = tid >> 4;               // 0..15
        const int c4  = tid & 15;               // float4 slot
        const floatx4 v = *(const floatx4*)&ob[row * 68 + c4 * 4];
        floatx4* dst = (floatx4*)&out[((size_t)(batch * MPTS + m0 + row)) * NC + c4 * 4];
        __builtin_nontemporal_store(v, dst);    // out never re-read: bypass L2
    }
}

extern "C" void kernel_launch(void* const* d_in, const int* in_sizes, int n_in,
                              void* d_out, int out_size, void* d_ws, size_t ws_size,
                              hipStream_t stream) {
    const float* points   = (const float*)d_in[0];
    const float* features = (const float*)d_in[1];
    const float* outpts   = (const float*)d_in[2];
    const float* kpts     = (const float*)d_in[3];
    const float* kvals    = (const float*)d_in[4];
    const int*   nbr      = (const int*)d_in[5];
    float* out = (float*)d_out;

    unsigned short* vp     = (unsigned short*)d_ws;                   // 131072 B
    unsigned short* featbf = (unsigned short*)((char*)d_ws + 131072); // 8 MB

    prep_kernel<<<2080, 256, 0, stream>>>(kvals, features, vp, featbf);

    const int blocks = BATCH * (MPTS / 16);   // 4096
    kpconv_kernel<<<blocks, 256, 0, stream>>>(points, featbf, outpts, kpts, vp, nbr, out);
}

// Round 11
// 136.689 us; speedup vs baseline: 1.0268x; 1.0268x over previous
//
#include <hip/hip_runtime.h>

#define BATCH 4
#define NPTS 16384
#define MPTS 16384
#define NH 32
#define NK 15
#define NF 64
#define NC 64

typedef short short8 __attribute__((ext_vector_type(8)));
typedef float floatx4 __attribute__((ext_vector_type(4)));

__device__ __forceinline__ unsigned short f2bf(float x) {
    unsigned int u = __builtin_bit_cast(unsigned int, x);
    u = u + 0x7FFFu + ((u >> 16) & 1u);   // RNE
    return (unsigned short)(u >> 16);
}

// pack two floats -> bf16x2 dword by truncation (1 v_perm)
__device__ __forceinline__ unsigned pack_trunc(float lo, float hi) {
    return __builtin_amdgcn_perm(__builtin_bit_cast(unsigned, hi),
                                 __builtin_bit_cast(unsigned, lo), 0x07060302u);
}

// ---------- fused prep: blocks [0,32) = V re-layout; [32, 2080) = feat fp32->bf16 ----------
__global__ void prep_kernel(const float* __restrict__ kv, const float* __restrict__ feat,
                            unsigned short* __restrict__ vp, unsigned short* __restrict__ featbf) {
    if (blockIdx.x < 32) {
        // kappa = f*16 + k (k padded to 16, zero for k==15). KF = 1024 -> 32 mfma steps.
        const int gid = blockIdx.x * 256 + threadIdx.x;        // 8192 threads
        const int lane = gid & 63;
        const int ct   = (gid >> 6) & 3;
        const int kk   = gid >> 8;                             // 0..31
        const int c    = ct * 16 + (lane & 15);
        const int kap0 = kk * 32 + (lane >> 4) * 8;
        unsigned int o[4];
        #pragma unroll
        for (int jj = 0; jj < 4; jj++) {
            unsigned short lo, hi;
            {
                const int kap = kap0 + jj * 2;
                const int f = kap >> 4, k = kap & 15;
                lo = (k < NK) ? f2bf(kv[((size_t)(k * NF + f)) * NC + c]) : (unsigned short)0;
            }
            {
                const int kap = kap0 + jj * 2 + 1;
                const int f = kap >> 4, k = kap & 15;
                hi = (k < NK) ? f2bf(kv[((size_t)(k * NF + f)) * NC + c]) : (unsigned short)0;
            }
            o[jj] = (unsigned)lo | ((unsigned)hi << 16);
        }
        *(uint4*)(vp + (size_t)gid * 8) = make_uint4(o[0], o[1], o[2], o[3]);
    } else {
        const int gid = (blockIdx.x - 32) * 256 + threadIdx.x; // 524288 threads x 8 elems
        const size_t base = (size_t)gid * 8;
        float4 a = *(const float4*)(feat + base);
        float4 b = *(const float4*)(feat + base + 4);
        uint4 o;
        o.x = (unsigned)f2bf(a.x) | ((unsigned)f2bf(a.y) << 16);
        o.y = (unsigned)f2bf(a.z) | ((unsigned)f2bf(a.w) << 16);
        o.z = (unsigned)f2bf(b.x) | ((unsigned)f2bf(b.y) << 16);
        o.w = (unsigned)f2bf(b.z) | ((unsigned)f2bf(b.w) << 16);
        *(uint4*)(featbf + base) = o;
    }
}

// ---------- main kernel (round-9 skeleton + rel4 skew + depth-2 prefetch) ----------
__global__ __launch_bounds__(256, 5) void kpconv_kernel(
    const float* __restrict__ points,          // [B,N,3]
    const unsigned short* __restrict__ featbf, // [B,N,F] bf16 (ws)
    const float* __restrict__ outpts,          // [B,M,3]
    const float* __restrict__ kpts,            // [K,3]
    const unsigned short* __restrict__ vp,     // einsum2 B-frag-ordered V bf16 (ws)
    const int*   __restrict__ nbr,             // [B,M,H]
    float* __restrict__ out)                   // [B,M,C]
{
    // awf: wf in einsum2 A-frag order for ONE kappa-half: [kk 0..15][chunk(swizzled)][8]
    // Prologue aliases it as skewed rel4 (574 float4 = 9184 B); epilogue as ob[16*68] float.
    __shared__ __align__(16) unsigned short awf[16 * 512];    // 16384 B
    // feat_s per wave: [floc 0..31][h 0..31 bf16] row stride 36 shorts (+pad)
    __shared__ __align__(16) unsigned short feat_s[4 * 1160]; //  9280 B
    __shared__ int   idx_s[512];                              //  2048 B
    __shared__ float opt_s[48];
    __shared__ float kp_s[48];

    const int tid   = threadIdx.x;
    // XCD-aware partition: round-robin dispatch sends blockIdx ≡ x (mod 8) to XCD x,
    // so batch = blockIdx & 3 pins each XCD's L2 to a single batch's 2 MB feature slice.
    const int batch = blockIdx.x & 3;
    const int m0    = (blockIdx.x >> 2) << 4;

    if (tid < 48) kp_s[tid] = (tid < 45) ? kpts[tid] : 1e9f;   // sentinel -> w=0 for k=15
    if (tid >= 64 && tid < 112)
        opt_s[tid - 64] = outpts[(size_t)(batch * MPTS + m0) * 3 + (tid - 64)];
    {
        const size_t nb = (size_t)(batch * MPTS + m0) * NH;
        idx_s[tid]       = nbr[nb + tid];
        idx_s[256 + tid] = nbr[nb + 256 + tid];
    }
    __syncthreads();   // B1: idx/opt/kp ready

    const int g    = tid >> 6;    // wave id; feat_s partition g is wave-private
    const int lane = tid & 63;
    const int cl   = lane & 15;
    const int q    = lane >> 4;
    const int sa   = cl;          // h-pair handled by this lane in staging
    const int sfc  = q;           // f-chunk of 8 shorts in staging

    const unsigned short* fbase = featbf + (size_t)(batch * NPTS) * NF;

    // ---- issue iter-0 AND iter-1 gathers immediately (depth-2 pipeline head) ----
    uint4 praA, prbA, praB, prbB;
    {
        const int srow0 = (0 * 4 + g) * 32 + sa * 2;           // it=0: r=0, fh=0
        const int ida0 = idx_s[srow0], idb0 = idx_s[srow0 + 1];
        praA = *(const uint4*)(fbase + (size_t)ida0 * NF + sfc * 8);
        prbA = *(const uint4*)(fbase + (size_t)idb0 * NF + sfc * 8);
        const int srow1 = (1 * 4 + g) * 32 + sa * 2;           // it=1: r=1, fh=0
        const int ida1 = idx_s[srow1], idb1 = idx_s[srow1 + 1];
        praB = *(const uint4*)(fbase + (size_t)ida1 * NF + sfc * 8);
        prbB = *(const uint4*)(fbase + (size_t)idb1 * NF + sfc * 8);
    }

    // ---- stage rel coords into awf alias (skewed: row -> row + (row>>3)) ----
    // skew makes the af-compute broadcast reads hit 4 disjoint bank windows per instr
    float4* rel4 = (float4*)awf;
    #pragma unroll
    for (int rr = 0; rr < 2; rr++) {
        const int row = tid * 2 + rr;            // 0..511 = p*32 + h
        const int id  = idx_s[row];
        const int pm  = row >> 5;
        const float* pp = points + ((size_t)(batch * NPTS) + id) * 3;
        rel4[row + (row >> 3)] = make_float4(pp[0] - opt_s[pm * 3 + 0],
                                             pp[1] - opt_s[pm * 3 + 1],
                                             pp[2] - opt_s[pm * 3 + 2], 0.f);
    }
    __syncthreads();   // B2: rel ready

    // ---- compute all w A-frags for this wave's 4 points (held in registers) ----
    short8 af[4];
    {
        const float kx = kp_s[cl * 3 + 0];
        const float ky = kp_s[cl * 3 + 1];
        const float kz = kp_s[cl * 3 + 2];
        #pragma unroll
        for (int rp = 0; rp < 4; rp++) {
            const int p = rp * 4 + g;
            float wv[8];
            #pragma unroll
            for (int j = 0; j < 8; j++) {
                // row = p*32 + q*8 + j  ->  skewed index 36p + 9q + j
                const float4 rr = rel4[36 * p + 9 * q + j];    // broadcast across cl
                const float dx = rr.x - kx, dy = rr.y - ky, dz = rr.z - kz;
                const float d2 = dx * dx + dy * dy + dz * dz;
                wv[j] = fmaxf(1.f - __builtin_amdgcn_sqrtf(d2), 0.f);  // EXTENT=1
            }
            uint4 ua;
            ua.x = pack_trunc(wv[0], wv[1]);
            ua.y = pack_trunc(wv[2], wv[3]);
            ua.z = pack_trunc(wv[4], wv[5]);
            ua.w = pack_trunc(wv[6], wv[7]);
            af[rp] = __builtin_bit_cast(short8, ua);
        }
    }
    __syncthreads();   // B3: rel4 dead -> awf free for einsum1 output

    floatx4 acc0 = {0.f, 0.f, 0.f, 0.f};
    floatx4 acc1 = {0.f, 0.f, 0.f, 0.f};
    const unsigned short* vpg = vp + g * 512 + lane * 8;
    unsigned short* dp = &feat_s[g * 1160 + sfc * 288 + sa * 2];   // sfc*8 rows of 36

    #pragma unroll
    for (int it = 0; it < 8; it++) {
        const int r  = it & 3;      // round (4 points each)
        const int p  = r * 4 + g;

        // (a) stage this iter's f-half from prefetched regs (wave-private LDS, no barrier)
        *(unsigned*)(dp + 0 * 36) = __builtin_amdgcn_perm(prbA.x, praA.x, 0x05040100u);
        *(unsigned*)(dp + 1 * 36) = __builtin_amdgcn_perm(prbA.x, praA.x, 0x07060302u);
        *(unsigned*)(dp + 2 * 36) = __builtin_amdgcn_perm(prbA.y, praA.y, 0x05040100u);
        *(unsigned*)(dp + 3 * 36) = __builtin_amdgcn_perm(prbA.y, praA.y, 0x07060302u);
        *(unsigned*)(dp + 4 * 36) = __builtin_amdgcn_perm(prbA.z, praA.z, 0x05040100u);
        *(unsigned*)(dp + 5 * 36) = __builtin_amdgcn_perm(prbA.z, praA.z, 0x07060302u);
        *(unsigned*)(dp + 6 * 36) = __builtin_amdgcn_perm(prbA.w, praA.w, 0x05040100u);
        *(unsigned*)(dp + 7 * 36) = __builtin_amdgcn_perm(prbA.w, praA.w, 0x07060302u);

        // (b) rotate pipeline and prefetch it+2 (fully unrolled -> rotation is free)
        praA = praB; prbA = prbB;
        if (it < 6) {
            const int nit = it + 2;
            const int nfh = nit >> 2, nr = nit & 3;
            const int srow = (nr * 4 + g) * 32 + sa * 2;
            const int id0 = idx_s[srow], id1 = idx_s[srow + 1];
            praB = *(const uint4*)(fbase + (size_t)id0 * NF + nfh * 32 + sfc * 8);
            prbB = *(const uint4*)(fbase + (size_t)id1 * NF + nfh * 32 + sfc * 8);
        }

        // (c) einsum1: 2 f-tiles of 16 for point p
        #pragma unroll
        for (int t = 0; t < 2; t++) {
            const uint4 ub = *(const uint4*)&feat_s[g * 1160 + (t * 16 + cl) * 36 + q * 8];
            floatx4 dd = {0.f, 0.f, 0.f, 0.f};
            dd = __builtin_amdgcn_mfma_f32_16x16x32_bf16(af[r], __builtin_bit_cast(short8, ub), dd, 0, 0, 0);
            const int kk    = 8 * t + (cl >> 1);               // local kappa-chunk 0..15
            const int q2    = (2 * cl + (q >> 1)) & 3;
            const int chunk = (p ^ kk) | (q2 << 4);
            unsigned* wp = (unsigned*)awf + kk * 256 + chunk * 4 + (q & 1) * 2;
            wp[0] = pack_trunc(dd[0], dd[1]);
            wp[1] = pack_trunc(dd[2], dd[3]);
        }

        // (d) at f-half boundary: einsum2 partial over this kappa-half
        if (it == 3) {
            __syncthreads();   // B4: awf (fh=0) complete
            #pragma unroll 4
            for (int kk = 0; kk < 16; kk++) {
                const int chunk = (cl ^ kk) | (lane & 48);
                const uint4 uA = *(const uint4*)&awf[kk * 512 + chunk * 8];
                const uint4 uB = *(const uint4*)(vpg + (size_t)kk * 2048);
                if (kk & 1)
                    acc1 = __builtin_amdgcn_mfma_f32_16x16x32_bf16(
                        __builtin_bit_cast(short8, uA), __builtin_bit_cast(short8, uB), acc1, 0, 0, 0);
                else
                    acc0 = __builtin_amdgcn_mfma_f32_16x16x32_bf16(
                        __builtin_bit_cast(short8, uA), __builtin_bit_cast(short8, uB), acc0, 0, 0, 0);
            }
            __syncthreads();   // B5: einsum2 reads done -> awf reusable for fh=1
        }
    }

    __syncthreads();   // B6: awf (fh=1) complete
    #pragma unroll 4
    for (int kk = 0; kk < 16; kk++) {
        const int chunk = (cl ^ kk) | (lane & 48);
        const uint4 uA = *(const uint4*)&awf[kk * 512 + chunk * 8];
        const uint4 uB = *(const uint4*)(vpg + (size_t)(16 + kk) * 2048);
        if (kk & 1)
            acc1 = __builtin_amdgcn_mfma_f32_16x16x32_bf16(
                __builtin_bit_cast(short8, uA), __builtin_bit_cast(short8, uB), acc1, 0, 0, 0);
        else
            acc0 = __builtin_amdgcn_mfma_f32_16x16x32_bf16(
                __builtin_bit_cast(short8, uA), __builtin_bit_cast(short8, uB), acc0, 0, 0, 0);
    }

    // ---- coalesced epilogue: stage via awf (stride-68 skew), store full 256B rows ----
    __syncthreads();   // B7: all einsum2 reads of awf done
    float* ob = (float*)awf;                    // need 16*68 = 1088 floats (4352 B)
    #pragma unroll
    for (int ri = 0; ri < 4; ri++)
        ob[(q * 4 + ri) * 68 + g * 16 + cl] = acc0[ri] + acc1[ri];
    __syncthreads();   // B8: staged
    {
        const int row = tid >> 4;               // 0..15
        const int c4  = tid & 15;               // float4 slot
        const floatx4 v = *(const floatx4*)&ob[row * 68 + c4 * 4];
        floatx4* dst = (floatx4*)&out[((size_t)(batch * MPTS + m0 + row)) * NC + c4 * 4];
        __builtin_nontemporal_store(v, dst);    // out never re-read: bypass L2
    }
}

extern "C" void kernel_launch(void* const* d_in, const int* in_sizes, int n_in,
                              void* d_out, int out_size, void* d_ws, size_t ws_size,
                              hipStream_t stream) {
    const float* points   = (const float*)d_in[0];
    const float* features = (const float*)d_in[1];
    const float* outpts   = (const float*)d_in[2];
    const float* kpts     = (const float*)d_in[3];
    const float* kvals    = (const float*)d_in[4];
    const int*   nbr      = (const int*)d_in[5];
    float* out = (float*)d_out;

    unsigned short* vp     = (unsigned short*)d_ws;                   // 131072 B
    unsigned short* featbf = (unsigned short*)((char*)d_ws + 131072); // 8 MB

    prep_kernel<<<2080, 256, 0, stream>>>(kvals, features, vp, featbf);

    const int blocks = BATCH * (MPTS / 16);   // 4096
    kpconv_kernel<<<blocks, 256, 0, stream>>>(points, featbf, outpts, kpts, vp, nbr, out);
}